// Round 1
// baseline (587.797 us; speedup 1.0000x reference)
//
#include <hip/hip_runtime.h>

#define B_ 8
#define CIN 64
#define COUT 64
#define H_ 128
#define W_ 128
#define HW (H_*W_)
#define KK 9

// ---------------- Kernel 1: offsets = conv3x3(x, w_off) + b_off  (18 out ch) ----------------
__global__ __launch_bounds__(256) void k_off(const float* __restrict__ x,
                                             const float* __restrict__ wof,
                                             const float* __restrict__ bof,
                                             float* __restrict__ off) {
    int idx = blockIdx.x * 256 + threadIdx.x;   // over B*H*W
    int wp = idx & (W_ - 1);
    int hp = (idx >> 7) & (H_ - 1);
    int bb = idx >> 14;
    const float* xb = x + (size_t)bb * CIN * HW;

    float acc[18];
#pragma unroll
    for (int oc = 0; oc < 18; ++oc) acc[oc] = bof[oc];

    for (int ic = 0; ic < CIN; ++ic) {
        float v[9];
#pragma unroll
        for (int dy = 0; dy < 3; ++dy) {
            int yy = hp + dy - 1;
#pragma unroll
            for (int dx = 0; dx < 3; ++dx) {
                int xx = wp + dx - 1;
                bool ok = ((unsigned)yy < H_) && ((unsigned)xx < W_);
                v[dy * 3 + dx] = ok ? xb[ic * HW + yy * W_ + xx] : 0.f;
            }
        }
        // weight index is wave-uniform -> scalar loads
#pragma unroll
        for (int oc = 0; oc < 18; ++oc) {
            const float* wp2 = wof + ((oc * CIN) + ic) * 9;
#pragma unroll
            for (int t = 0; t < 9; ++t) acc[oc] += wp2[t] * v[t];
        }
    }
#pragma unroll
    for (int oc = 0; oc < 18; ++oc)
        off[((size_t)bb * 18 + oc) * HW + hp * W_ + wp] = acc[oc];
}

// ---------------- Kernel 2: deformable bilinear sampling, summed over KK taps ----------------
__global__ __launch_bounds__(256) void k_sample(const float* __restrict__ x,
                                                const float* __restrict__ off,
                                                float* __restrict__ smp) {
    int idx = blockIdx.x * 256 + threadIdx.x;   // over B*C*H*W, w fastest
    int wp = idx & (W_ - 1);
    int hp = (idx >> 7) & (H_ - 1);
    int c  = (idx >> 14) & 63;
    int bb = idx >> 20;

    const float* xp = x + ((size_t)bb * CIN + c) * HW;
    const float* op = off + (size_t)bb * 18 * HW + hp * W_ + wp;

    float acc = 0.f;
#pragma unroll
    for (int k = 0; k < KK; ++k) {
        float ox = op[(2 * k) * HW];        // channel 2k   -> x offset
        float oy = op[(2 * k + 1) * HW];    // channel 2k+1 -> y offset
        float xs = (float)wp + ox;
        float ys = (float)hp + oy;
        float x0f = floorf(xs), y0f = floorf(ys);
        float wx1 = xs - x0f, wy1 = ys - y0f;
        float wx0 = 1.f - wx1, wy0 = 1.f - wy1;
        int x0 = (int)x0f, y0 = (int)y0f;
        int x1 = x0 + 1,   y1 = y0 + 1;

        float v00 = (((unsigned)y0 < H_) && ((unsigned)x0 < W_)) ? xp[y0 * W_ + x0] : 0.f;
        float v01 = (((unsigned)y0 < H_) && ((unsigned)x1 < W_)) ? xp[y0 * W_ + x1] : 0.f;
        float v10 = (((unsigned)y1 < H_) && ((unsigned)x0 < W_)) ? xp[y1 * W_ + x0] : 0.f;
        float v11 = (((unsigned)y1 < H_) && ((unsigned)x1 < W_)) ? xp[y1 * W_ + x1] : 0.f;

        acc += wy0 * (wx0 * v00 + wx1 * v01) + wy1 * (wx0 * v10 + wx1 * v11);
    }
    smp[idx] = acc;
}

// ---------------- Kernel 3: out = conv3x3(sampled, w_reg) + b_reg  (64 out ch, 32 per block-row) ----------------
__global__ __launch_bounds__(256) void k_conv2(const float* __restrict__ smp,
                                               const float* __restrict__ wrg,
                                               const float* __restrict__ brg,
                                               float* __restrict__ out) {
    int idx = blockIdx.x * 256 + threadIdx.x;   // over B*H*W
    int ocg = blockIdx.y;                        // 0..1 -> oc base 0/32
    int wp = idx & (W_ - 1);
    int hp = (idx >> 7) & (H_ - 1);
    int bb = idx >> 14;
    const float* sb = smp + (size_t)bb * CIN * HW;

    float acc[32];
#pragma unroll
    for (int i = 0; i < 32; ++i) acc[i] = brg[ocg * 32 + i];

    for (int ic = 0; ic < CIN; ++ic) {
        float v[9];
#pragma unroll
        for (int dy = 0; dy < 3; ++dy) {
            int yy = hp + dy - 1;
#pragma unroll
            for (int dx = 0; dx < 3; ++dx) {
                int xx = wp + dx - 1;
                bool ok = ((unsigned)yy < H_) && ((unsigned)xx < W_);
                v[dy * 3 + dx] = ok ? sb[ic * HW + yy * W_ + xx] : 0.f;
            }
        }
#pragma unroll
        for (int i = 0; i < 32; ++i) {
            const float* wp2 = wrg + (((ocg * 32 + i) * CIN) + ic) * 9;
#pragma unroll
            for (int t = 0; t < 9; ++t) acc[i] += wp2[t] * v[t];
        }
    }
#pragma unroll
    for (int i = 0; i < 32; ++i)
        out[((size_t)bb * COUT + ocg * 32 + i) * HW + hp * W_ + wp] = acc[i];
}

extern "C" void kernel_launch(void* const* d_in, const int* in_sizes, int n_in,
                              void* d_out, int out_size, void* d_ws, size_t ws_size,
                              hipStream_t stream) {
    const float* x   = (const float*)d_in[0];
    const float* wof = (const float*)d_in[1];
    const float* bof = (const float*)d_in[2];
    const float* wrg = (const float*)d_in[3];
    const float* brg = (const float*)d_in[4];
    float* out = (float*)d_out;

    // workspace layout: offsets (B*18*HW floats) then sampled (B*64*HW floats) = ~41 MB
    float* off = (float*)d_ws;
    float* smp = off + (size_t)B_ * 18 * HW;

    k_off   <<<dim3((B_ * HW) / 256),          256, 0, stream>>>(x, wof, bof, off);
    k_sample<<<dim3((B_ * CIN * HW) / 256),    256, 0, stream>>>(x, off, smp);
    k_conv2 <<<dim3((B_ * HW) / 256, 2),       256, 0, stream>>>(smp, wrg, brg, out);
}

// Round 2
// 277.532 us; speedup vs baseline: 2.1179x; 2.1179x over previous
//
#include <hip/hip_runtime.h>

#define B_ 8
#define CIN 64
#define COUT 64
#define H_ 128
#define W_ 128
#define HW (H_*W_)

typedef __attribute__((ext_vector_type(8))) short short8;   // 8 bf16 (4 VGPRs)
typedef __attribute__((ext_vector_type(4))) float f32x4;    // MFMA acc

__device__ __forceinline__ short f2bf(float f) {
    unsigned u = __float_as_uint(f);
    unsigned r = (u + 0x7fffu + ((u >> 16) & 1u)) >> 16;   // RNE
    return (short)r;
}
__device__ __forceinline__ float bf2f(short s) {
    return __uint_as_float(((unsigned)(unsigned short)s) << 16);
}
__device__ __forceinline__ short8 ld8(const short* p, bool v) {
    short8 z = {0,0,0,0,0,0,0,0};
    return v ? *(const short8*)p : z;
}

// ---------- prep: weights -> [d][oc][ic] bf16 ----------
__global__ __launch_bounds__(256) void k_prep(const float* __restrict__ wof,
                                              const float* __restrict__ wrg,
                                              short* __restrict__ wt1,   // [9][32][64]
                                              short* __restrict__ wt2) { // [9][64][64]
    int i = blockIdx.x * 256 + threadIdx.x;
    if (i < 9 * 32 * 64) {
        int d = i / 2048, r = i % 2048, oc = r >> 6, ic = r & 63;
        float v = (oc < 18) ? wof[(oc * 64 + ic) * 9 + d] : 0.f;
        wt1[i] = f2bf(v);
    }
    if (i < 9 * 64 * 64) {
        int d = i / 4096, r = i % 4096, oc = r >> 6, ic = r & 63;
        wt2[i] = f2bf(wrg[(oc * 64 + ic) * 9 + d]);
    }
}

// ---------- transpose: x NCHW fp32 -> NHWC bf16 ----------
__global__ __launch_bounds__(256) void k_tr(const float* __restrict__ x,
                                            short* __restrict__ xt) {
    __shared__ float tile[64 * 129];
    int bh = blockIdx.x;                           // b*128 + h
    const float* xp = x + (size_t)(bh >> 7) * (CIN * HW) + (bh & 127) * W_;
#pragma unroll
    for (int j = 0; j < 32; ++j) {
        int e = threadIdx.x + 256 * j;             // 8192 = 64c * 128w
        int cc = e >> 7, ww = e & 127;
        tile[cc * 129 + ww] = xp[cc * HW + ww];
    }
    __syncthreads();
    short* op = xt + (size_t)bh * 8192;            // [w][c]
#pragma unroll
    for (int j = 0; j < 32; ++j) {
        int e = threadIdx.x + 256 * j;
        int ww = e >> 6, cc = e & 63;
        op[e] = f2bf(tile[cc * 129 + ww]);
    }
}

// ---------- conv1 (offsets) via MFMA: N=32 (18 used), out bf16 [pix][18] ----------
__global__ __launch_bounds__(256) void k_conv1(const short* __restrict__ xt,
                                               const short* __restrict__ wt1,
                                               const float* __restrict__ bof,
                                               unsigned short* __restrict__ offb) {
    int wave = (blockIdx.x * 256 + threadIdx.x) >> 6;   // one m-tile (16 px) per wave
    int lane = threadIdx.x & 63;
    int m = lane & 15, quad = lane >> 4;
    int p0 = wave * 16;
    int bb = p0 >> 14, h = (p0 >> 7) & 127, w0 = p0 & 127;
    int w = w0 + m;

    f32x4 acc[2];
#pragma unroll
    for (int nt = 0; nt < 2; ++nt) {
        int oc = m + 16 * nt;
        float bv = (oc < 18) ? bof[oc] : 0.f;
        acc[nt][0] = bv; acc[nt][1] = bv; acc[nt][2] = bv; acc[nt][3] = bv;
    }

#pragma unroll
    for (int d = 0; d < 9; ++d) {
        int dy = d / 3 - 1, dx = d % 3 - 1;
        int y = h + dy, xx = w + dx;
        bool valid = ((unsigned)y < H_) && ((unsigned)xx < W_);
        const short* arow = xt + ((size_t)(((bb << 7) + y) << 7) + xx) * 64;
#pragma unroll
        for (int c = 0; c < 2; ++c) {
            short8 a = ld8(arow + c * 32 + quad * 8, valid);
#pragma unroll
            for (int nt = 0; nt < 2; ++nt) {
                int oc = m + 16 * nt;
                short8 b = *(const short8*)(wt1 + ((d * 32 + oc) * 64 + c * 32 + quad * 8));
                acc[nt] = __builtin_amdgcn_mfma_f32_16x16x32_bf16(a, b, acc[nt], 0, 0, 0);
            }
        }
    }
    // store: col=lane&15 (oc), row=quad*4+reg (pixel)
#pragma unroll
    for (int nt = 0; nt < 2; ++nt) {
        int oc = m + 16 * nt;
        if (oc < 18) {
#pragma unroll
            for (int r = 0; r < 4; ++r) {
                int p = p0 + quad * 4 + r;
                offb[(size_t)p * 18 + oc] = (unsigned short)f2bf(acc[nt][r]);
            }
        }
    }
}

// ---------- deformable bilinear sample: thread per (pixel, 8ch), NHWC bf16 out ----------
__global__ __launch_bounds__(256) void k_sample(const short* __restrict__ xt,
                                                const unsigned short* __restrict__ offb,
                                                short* __restrict__ smp) {
    int t = blockIdx.x * 256 + threadIdx.x;     // B*HW*8 threads
    int ck = t & 7;                              // channel chunk (8 ch)
    int pix = t >> 3;
    int bb = pix >> 14, h = (pix >> 7) & 127, w = pix & 127;
    const short* xb = xt + (size_t)bb * (HW * 64) + ck * 8;

    const unsigned* op = (const unsigned*)(offb + (size_t)pix * 18);
    unsigned ow[9];
#pragma unroll
    for (int j = 0; j < 9; ++j) ow[j] = op[j];

    float acc[8];
#pragma unroll
    for (int i = 0; i < 8; ++i) acc[i] = 0.f;

#pragma unroll
    for (int k = 0; k < 9; ++k) {
        float ox = bf2f((short)(ow[k] & 0xffff));
        float oy = bf2f((short)(ow[k] >> 16));
        float xs = (float)w + ox, ys = (float)h + oy;
        float x0f = floorf(xs), y0f = floorf(ys);
        float wx1 = xs - x0f, wx0 = 1.f - wx1;
        float wy1 = ys - y0f, wy0 = 1.f - wy1;
        int x0 = (int)x0f, y0 = (int)y0f;
#pragma unroll
        for (int dyy = 0; dyy < 2; ++dyy) {
#pragma unroll
            for (int dxx = 0; dxx < 2; ++dxx) {
                int yy = y0 + dyy, xx = x0 + dxx;
                bool v = ((unsigned)yy < H_) && ((unsigned)xx < W_);
                short8 s = ld8(xb + ((size_t)yy * W_ + xx) * 64, v);
                float wg = (dyy ? wy1 : wy0) * (dxx ? wx1 : wx0);
#pragma unroll
                for (int i = 0; i < 8; ++i) acc[i] += wg * bf2f(s[i]);
            }
        }
    }
    short8 o;
#pragma unroll
    for (int i = 0; i < 8; ++i) o[i] = f2bf(acc[i]);
    *(short8*)(smp + (size_t)pix * 64 + ck * 8) = o;
}

// ---------- conv2 via MFMA: per-wave 16m x 64n, out NCHW fp32 ----------
__global__ __launch_bounds__(256) void k_conv2(const short* __restrict__ smp,
                                               const short* __restrict__ wt2,
                                               const float* __restrict__ brg,
                                               float* __restrict__ out) {
    int wave = (blockIdx.x * 256 + threadIdx.x) >> 6;
    int lane = threadIdx.x & 63;
    int m = lane & 15, quad = lane >> 4;
    int p0 = wave * 16;
    int bb = p0 >> 14, h = (p0 >> 7) & 127, w0 = p0 & 127;
    int w = w0 + m;

    f32x4 acc[4];
#pragma unroll
    for (int nt = 0; nt < 4; ++nt) {
        float bv = brg[m + 16 * nt];
        acc[nt][0] = bv; acc[nt][1] = bv; acc[nt][2] = bv; acc[nt][3] = bv;
    }

#pragma unroll
    for (int d = 0; d < 9; ++d) {
        int dy = d / 3 - 1, dx = d % 3 - 1;
        int y = h + dy, xx = w + dx;
        bool valid = ((unsigned)y < H_) && ((unsigned)xx < W_);
        const short* arow = smp + ((size_t)(((bb << 7) + y) << 7) + xx) * 64;
#pragma unroll
        for (int c = 0; c < 2; ++c) {
            short8 a = ld8(arow + c * 32 + quad * 8, valid);
#pragma unroll
            for (int nt = 0; nt < 4; ++nt) {
                int oc = m + 16 * nt;
                short8 b = *(const short8*)(wt2 + ((d * 64 + oc) * 64 + c * 32 + quad * 8));
                acc[nt] = __builtin_amdgcn_mfma_f32_16x16x32_bf16(a, b, acc[nt], 0, 0, 0);
            }
        }
    }
    int hw0 = (p0 & 16383) + quad * 4;
#pragma unroll
    for (int nt = 0; nt < 4; ++nt) {
        int oc = m + 16 * nt;
        *(f32x4*)(out + ((size_t)(bb * 64 + oc) << 14) + hw0) = acc[nt];
    }
}

extern "C" void kernel_launch(void* const* d_in, const int* in_sizes, int n_in,
                              void* d_out, int out_size, void* d_ws, size_t ws_size,
                              hipStream_t stream) {
    const float* x   = (const float*)d_in[0];
    const float* wof = (const float*)d_in[1];
    const float* bof = (const float*)d_in[2];
    const float* wrg = (const float*)d_in[3];
    const float* brg = (const float*)d_in[4];
    float* out = (float*)d_out;

    // workspace layout (bytes), all 16B aligned:
    char* ws = (char*)d_ws;
    short* xt          = (short*)ws;                              // 16,777,216
    short* smp         = (short*)(ws + 16777216);                 // 16,777,216
    unsigned short* ob = (unsigned short*)(ws + 2 * 16777216);    //  4,718,592
    short* wt1         = (short*)(ws + 2 * 16777216 + 4718592);   //     36,864
    short* wt2         = (short*)(ws + 2 * 16777216 + 4718592 + 36864); // 73,728

    k_prep  <<<dim3(144),  256, 0, stream>>>(wof, wrg, wt1, wt2);
    k_tr    <<<dim3(B_ * H_), 256, 0, stream>>>(x, xt);
    k_conv1 <<<dim3((B_ * HW / 16) / 4), 256, 0, stream>>>(xt, wt1, bof, ob);
    k_sample<<<dim3((B_ * HW * 8) / 256), 256, 0, stream>>>(xt, ob, smp);
    k_conv2 <<<dim3((B_ * HW / 16) / 4), 256, 0, stream>>>(smp, wt2, brg, out);
}

// Round 3
// 208.271 us; speedup vs baseline: 2.8223x; 1.3326x over previous
//
#include <hip/hip_runtime.h>

#define B_ 8
#define CIN 64
#define COUT 64
#define H_ 128
#define W_ 128
#define HW (H_*W_)

typedef __attribute__((ext_vector_type(8))) short short8;   // 8 bf16 (4 VGPRs)
typedef __attribute__((ext_vector_type(4))) float f32x4;    // MFMA acc

__device__ __forceinline__ short f2bf(float f) {
    unsigned u = __float_as_uint(f);
    unsigned r = (u + 0x7fffu + ((u >> 16) & 1u)) >> 16;   // RNE
    return (short)r;
}
__device__ __forceinline__ float bf2f(short s) {
    return __uint_as_float(((unsigned)(unsigned short)s) << 16);
}

// ---------- prep: weights -> lane-linear bf16 frags: wt[((d*2+c)*NT+nt)*64+lane][8] ----------
template<int NT>
__device__ __forceinline__ void prep_one(const float* __restrict__ w, short* __restrict__ o,
                                         int i, int n_used) {
    // i = (((d*2+c)*NT + nt)*64 + lane)*8 + j
    int j = i & 7, lane = (i >> 3) & 63, rest = i >> 9;
    int nt = rest % NT, dc = rest / NT, c = dc & 1, d = dc >> 1;
    int oc = nt * 16 + (lane & 15);
    int ic = c * 32 + (lane >> 4) * 8 + j;
    float v = (oc < n_used) ? w[(oc * 64 + ic) * 9 + d] : 0.f;
    o[i] = f2bf(v);
}

__global__ __launch_bounds__(256) void k_prep(const float* __restrict__ wof,
                                              const float* __restrict__ wrg,
                                              short* __restrict__ wt1,   // 9*2*2*64*8
                                              short* __restrict__ wt2) { // 9*2*4*64*8
    int i = blockIdx.x * 256 + threadIdx.x;
    if (i < 9 * 2 * 2 * 512) prep_one<2>(wof, wt1, i, 18);
    if (i < 9 * 2 * 4 * 512) prep_one<4>(wrg, wt2, i, 64);
}

// ---------- transpose: x NCHW fp32 -> NHWC bf16 ----------
__global__ __launch_bounds__(256) void k_tr(const float* __restrict__ x,
                                            short* __restrict__ xt) {
    __shared__ float tile[64 * 129];
    int bh = blockIdx.x;                           // b*128 + h
    const float* xp = x + (size_t)(bh >> 7) * (CIN * HW) + (bh & 127) * W_;
#pragma unroll
    for (int j = 0; j < 32; ++j) {
        int e = threadIdx.x + 256 * j;             // 8192 = 64c * 128w
        int cc = e >> 7, ww = e & 127;
        tile[cc * 129 + ww] = xp[cc * HW + ww];
    }
    __syncthreads();
    short* op = xt + (size_t)bh * 8192;            // [w][c]
#pragma unroll
    for (int j = 0; j < 32; ++j) {
        int e = threadIdx.x + 256 * j;
        int ww = e >> 6, cc = e & 63;
        op[e] = f2bf(tile[cc * 129 + ww]);
    }
}

// ---------- conv via MFMA, LDS-staged: block = one (b,h) row of 128 px ----------
// src NHWC bf16. wt lane-linear. If TO_OFF: write bf16 [pix][18], else fp32 NCHW.
template<int NT, bool TO_OFF>
__global__ __launch_bounds__(256, 3) void k_conv(const short* __restrict__ src,
                                                 const short* __restrict__ wt,
                                                 const float* __restrict__ bias,
                                                 short* __restrict__ outb,
                                                 float* __restrict__ outf) {
    __shared__ short At[3 * 130 * 64];             // 49920 B, XOR-swizzled chunks
    int bh = blockIdx.x;
    int bb = bh >> 7, h = bh & 127;

    // stage 3 rows (h-1..h+1) x 130 px (x=-1..128) x 64 ch, branchless
#pragma unroll
    for (int it = 0; it < 13; ++it) {
        int s = threadIdx.x + it * 256;            // chunk slot: 3*130*8 = 3120
        if (s < 3120) {
            int r = s / 1040, rem = s % 1040;
            int px = rem >> 3, ck = rem & 7;
            int y = h - 1 + r, xx = px - 1;
            bool v = ((unsigned)y < H_) && ((unsigned)xx < W_);
            int yc = min(max(y, 0), H_ - 1), xc = min(max(xx, 0), W_ - 1);
            short8 val = *(const short8*)(src + ((((size_t)(bb << 7) + yc) << 7) + xc) * 64 + ck * 8);
            short8 z = {0,0,0,0,0,0,0,0};
            if (!v) val = z;
            *(short8*)(&At[(r * 130 + px) * 64 + ((ck ^ (px & 7)) << 3)]) = val;
        }
    }
    __syncthreads();

    int lane = threadIdx.x & 63;
    int wave = threadIdx.x >> 6;
    int m = lane & 15, quad = lane >> 4;
    int p0 = wave * 32;                            // 32 px per wave (2 m-tiles)

    f32x4 acc[2][NT];
#pragma unroll
    for (int nt = 0; nt < NT; ++nt) {
        int oc = nt * 16 + m;
        float bv = (!TO_OFF || oc < 18) ? bias[oc] : 0.f;
#pragma unroll
        for (int mt = 0; mt < 2; ++mt) {
            acc[mt][nt][0] = bv; acc[mt][nt][1] = bv;
            acc[mt][nt][2] = bv; acc[mt][nt][3] = bv;
        }
    }

#pragma unroll
    for (int d = 0; d < 9; ++d) {
        int dy = d / 3, dx = d % 3;
#pragma unroll
        for (int c = 0; c < 2; ++c) {
            short8 a[2];
#pragma unroll
            for (int mt = 0; mt < 2; ++mt) {
                int px = p0 + mt * 16 + m + dx;
                a[mt] = *(const short8*)(&At[(dy * 130 + px) * 64 + (((c * 4 + quad) ^ (px & 7)) << 3)]);
            }
#pragma unroll
            for (int nt = 0; nt < NT; ++nt) {
                short8 b = *(const short8*)(wt + ((((d * 2 + c) * NT + nt) * 64 + lane) << 3));
#pragma unroll
                for (int mt = 0; mt < 2; ++mt)
                    acc[mt][nt] = __builtin_amdgcn_mfma_f32_16x16x32_bf16(a[mt], b, acc[mt][nt], 0, 0, 0);
            }
        }
    }

    // C/D: col(oc within tile)=lane&15, row(pixel)=quad*4+reg
    if (TO_OFF) {
#pragma unroll
        for (int nt = 0; nt < NT; ++nt) {
            int oc = nt * 16 + m;
            if (oc < 18) {
#pragma unroll
                for (int mt = 0; mt < 2; ++mt) {
                    int p = bh * 128 + p0 + mt * 16 + quad * 4;
#pragma unroll
                    for (int r = 0; r < 4; ++r)
                        outb[(size_t)(p + r) * 18 + oc] = f2bf(acc[mt][nt][r]);
                }
            }
        }
    } else {
#pragma unroll
        for (int nt = 0; nt < NT; ++nt) {
            int oc = nt * 16 + m;
#pragma unroll
            for (int mt = 0; mt < 2; ++mt) {
                int wpix = p0 + mt * 16 + quad * 4;
                *(f32x4*)(outf + (((size_t)(bb * 64 + oc)) << 14) + (h << 7) + wpix) = acc[mt][nt];
            }
        }
    }
}

// ---------- deformable bilinear sample: thread per (pixel, 8ch), branchless ----------
__global__ __launch_bounds__(256, 4) void k_sample(const short* __restrict__ xt,
                                                   const short* __restrict__ offb,
                                                   short* __restrict__ smp) {
    int t = blockIdx.x * 256 + threadIdx.x;     // B*HW*8 threads
    int ck = t & 7;                              // channel chunk (8 ch)
    int pix = t >> 3;
    int bb = pix >> 14, h = (pix >> 7) & 127, w = pix & 127;
    const short* xb = xt + ((size_t)bb << 20) + ck * 8;

    const unsigned* op = (const unsigned*)(offb + (size_t)pix * 18);
    unsigned ow[9];
#pragma unroll
    for (int j = 0; j < 9; ++j) ow[j] = op[j];

    float acc[8];
#pragma unroll
    for (int i = 0; i < 8; ++i) acc[i] = 0.f;

#pragma unroll
    for (int k = 0; k < 9; ++k) {
        float ox = bf2f((short)(ow[k] & 0xffff));
        float oy = bf2f((short)(ow[k] >> 16));
        float xs = (float)w + ox, ys = (float)h + oy;
        float x0f = floorf(xs), y0f = floorf(ys);
        float wx1 = xs - x0f, wx0 = 1.f - wx1;
        float wy1 = ys - y0f, wy0 = 1.f - wy1;
        int x0 = (int)x0f, y0 = (int)y0f;
        int x1 = x0 + 1, y1 = y0 + 1;
        int x0c = min(max(x0, 0), W_ - 1), x1c = min(max(x1, 0), W_ - 1);
        int y0c = min(max(y0, 0), H_ - 1), y1c = min(max(y1, 0), H_ - 1);
        bool vx0 = ((unsigned)x0 < W_), vx1 = ((unsigned)x1 < W_);
        bool vy0 = ((unsigned)y0 < H_), vy1 = ((unsigned)y1 < H_);
        float w00 = (vy0 && vx0) ? wy0 * wx0 : 0.f;
        float w01 = (vy0 && vx1) ? wy0 * wx1 : 0.f;
        float w10 = (vy1 && vx0) ? wy1 * wx0 : 0.f;
        float w11 = (vy1 && vx1) ? wy1 * wx1 : 0.f;
        short8 s00 = *(const short8*)(xb + ((size_t)(y0c * W_ + x0c) << 6));
        short8 s01 = *(const short8*)(xb + ((size_t)(y0c * W_ + x1c) << 6));
        short8 s10 = *(const short8*)(xb + ((size_t)(y1c * W_ + x0c) << 6));
        short8 s11 = *(const short8*)(xb + ((size_t)(y1c * W_ + x1c) << 6));
#pragma unroll
        for (int i = 0; i < 8; ++i)
            acc[i] += w00 * bf2f(s00[i]) + w01 * bf2f(s01[i])
                    + w10 * bf2f(s10[i]) + w11 * bf2f(s11[i]);
    }
    short8 o;
#pragma unroll
    for (int i = 0; i < 8; ++i) o[i] = f2bf(acc[i]);
    *(short8*)(smp + (size_t)pix * 64 + ck * 8) = o;
}

extern "C" void kernel_launch(void* const* d_in, const int* in_sizes, int n_in,
                              void* d_out, int out_size, void* d_ws, size_t ws_size,
                              hipStream_t stream) {
    const float* x   = (const float*)d_in[0];
    const float* wof = (const float*)d_in[1];
    const float* bof = (const float*)d_in[2];
    const float* wrg = (const float*)d_in[3];
    const float* brg = (const float*)d_in[4];
    float* out = (float*)d_out;

    char* ws = (char*)d_ws;
    short* xt   = (short*)ws;                                   // 16,777,216 B
    short* smp  = (short*)(ws + 16777216);                      // 16,777,216 B
    short* offb = (short*)(ws + 2 * 16777216);                  //  4,718,592 B
    short* wt1  = (short*)(ws + 2 * 16777216 + 4718592);        //     36,864 B
    short* wt2  = (short*)(ws + 2 * 16777216 + 4718592 + 36864);//     73,728 B

    k_prep <<<dim3(144), 256, 0, stream>>>(wof, wrg, wt1, wt2);
    k_tr   <<<dim3(B_ * H_), 256, 0, stream>>>(x, xt);
    k_conv<2, true>  <<<dim3(B_ * H_), 256, 0, stream>>>(xt, wt1, bof, offb, nullptr);
    k_sample<<<dim3((B_ * HW * 8) / 256), 256, 0, stream>>>(xt, offb, smp);
    k_conv<4, false> <<<dim3(B_ * H_), 256, 0, stream>>>(smp, wt2, brg, nullptr, out);
}

// Round 4
// 196.100 us; speedup vs baseline: 2.9974x; 1.0621x over previous
//
#include <hip/hip_runtime.h>

#define B_ 8
#define CIN 64
#define COUT 64
#define H_ 128
#define W_ 128
#define HW (H_*W_)

typedef __attribute__((ext_vector_type(8))) short short8;   // 8 bf16 (4 VGPRs)
typedef __attribute__((ext_vector_type(4))) float f32x4;    // MFMA acc

__device__ __forceinline__ short f2bf(float f) {
    unsigned u = __float_as_uint(f);
    unsigned r = (u + 0x7fffu + ((u >> 16) & 1u)) >> 16;   // RNE
    return (short)r;
}
__device__ __forceinline__ float bf2f(short s) {
    return __uint_as_float(((unsigned)(unsigned short)s) << 16);
}

// ---------- prep: weights -> lane-linear bf16 frags: wt[((d*2+c)*NT+nt)*64+lane][8] ----------
template<int NT>
__device__ __forceinline__ void prep_one(const float* __restrict__ w, short* __restrict__ o,
                                         int i, int n_used) {
    int j = i & 7, lane = (i >> 3) & 63, rest = i >> 9;
    int nt = rest % NT, dc = rest / NT, c = dc & 1, d = dc >> 1;
    int oc = nt * 16 + (lane & 15);
    int ic = c * 32 + (lane >> 4) * 8 + j;
    float v = (oc < n_used) ? w[(oc * 64 + ic) * 9 + d] : 0.f;
    o[i] = f2bf(v);
}

__global__ __launch_bounds__(256) void k_prep(const float* __restrict__ wof,
                                              const float* __restrict__ wrg,
                                              short* __restrict__ wt1,   // 9*2*2*64*8
                                              short* __restrict__ wt2) { // 9*2*4*64*8
    int i = blockIdx.x * 256 + threadIdx.x;
    if (i < 9 * 2 * 2 * 512) prep_one<2>(wof, wt1, i, 18);
    if (i < 9 * 2 * 4 * 512) prep_one<4>(wrg, wt2, i, 64);
}

// ---------- transpose: x NCHW fp32 -> NHWC bf16 ----------
__global__ __launch_bounds__(256) void k_tr(const float* __restrict__ x,
                                            short* __restrict__ xt) {
    __shared__ float tile[64 * 129];
    int bh = blockIdx.x;                           // image-pinned: b = bh&7
    int bb = bh & 7, h = bh >> 3;
    const float* xp = x + (size_t)bb * (CIN * HW) + h * W_;
#pragma unroll
    for (int j = 0; j < 32; ++j) {
        int e = threadIdx.x + 256 * j;             // 8192 = 64c * 128w
        int cc = e >> 7, ww = e & 127;
        tile[cc * 129 + ww] = xp[cc * HW + ww];
    }
    __syncthreads();
    short* op = xt + (((size_t)(bb << 7) + h) << 13);   // [b][h][w][c]
#pragma unroll
    for (int j = 0; j < 32; ++j) {
        int e = threadIdx.x + 256 * j;
        int ww = e >> 6, cc = e & 63;
        op[e] = f2bf(tile[cc * 129 + ww]);
    }
}

// ---------- conv via MFMA, LDS-staged: block = one (b,h) row of 128 px, XCD-pinned by b ----------
template<int NT, bool TO_OFF>
__global__ __launch_bounds__(256, 3) void k_conv(const short* __restrict__ src,
                                                 const short* __restrict__ wt,
                                                 const float* __restrict__ bias,
                                                 short* __restrict__ outb,
                                                 float* __restrict__ outf) {
    __shared__ short At[3 * 130 * 64];             // 49920 B, XOR-swizzled chunks
    int bh = blockIdx.x;
    int bb = bh & 7, h = bh >> 3;                  // b = blk%8 -> XCD-pinned image

    // stage 3 rows (h-1..h+1) x 130 px (x=-1..128) x 64 ch, branchless
#pragma unroll
    for (int it = 0; it < 13; ++it) {
        int s = threadIdx.x + it * 256;            // chunk slot: 3*130*8 = 3120
        if (s < 3120) {
            int r = s / 1040, rem = s % 1040;
            int px = rem >> 3, ck = rem & 7;
            int y = h - 1 + r, xx = px - 1;
            bool v = ((unsigned)y < H_) && ((unsigned)xx < W_);
            int yc = min(max(y, 0), H_ - 1), xc = min(max(xx, 0), W_ - 1);
            short8 val = *(const short8*)(src + ((((size_t)(bb << 7) + yc) << 7) + xc) * 64 + ck * 8);
            short8 z = {0,0,0,0,0,0,0,0};
            if (!v) val = z;
            *(short8*)(&At[(r * 130 + px) * 64 + ((ck ^ (px & 7)) << 3)]) = val;
        }
    }
    __syncthreads();

    int lane = threadIdx.x & 63;
    int wave = threadIdx.x >> 6;
    int m = lane & 15, quad = lane >> 4;
    int p0 = wave * 32;                            // 32 px per wave (2 m-tiles)

    f32x4 acc[2][NT];
#pragma unroll
    for (int nt = 0; nt < NT; ++nt) {
        int oc = nt * 16 + m;
        float bv = (!TO_OFF || oc < 18) ? bias[oc] : 0.f;
#pragma unroll
        for (int mt = 0; mt < 2; ++mt) {
            acc[mt][nt][0] = bv; acc[mt][nt][1] = bv;
            acc[mt][nt][2] = bv; acc[mt][nt][3] = bv;
        }
    }

#pragma unroll
    for (int d = 0; d < 9; ++d) {
        int dy = d / 3, dx = d % 3;
#pragma unroll
        for (int c = 0; c < 2; ++c) {
            short8 a[2];
#pragma unroll
            for (int mt = 0; mt < 2; ++mt) {
                int px = p0 + mt * 16 + m + dx;
                a[mt] = *(const short8*)(&At[(dy * 130 + px) * 64 + (((c * 4 + quad) ^ (px & 7)) << 3)]);
            }
#pragma unroll
            for (int nt = 0; nt < NT; ++nt) {
                short8 b = *(const short8*)(wt + ((((d * 2 + c) * NT + nt) * 64 + lane) << 3));
#pragma unroll
                for (int mt = 0; mt < 2; ++mt)
                    acc[mt][nt] = __builtin_amdgcn_mfma_f32_16x16x32_bf16(a[mt], b, acc[mt][nt], 0, 0, 0);
            }
        }
    }

    // C/D: col(oc within tile)=lane&15, row(pixel)=quad*4+reg
    int pixbase = (bb << 14) + (h << 7);
    if (TO_OFF) {
#pragma unroll
        for (int nt = 0; nt < NT; ++nt) {
            int oc = nt * 16 + m;
            if (oc < 18) {
#pragma unroll
                for (int mt = 0; mt < 2; ++mt) {
                    int p = pixbase + p0 + mt * 16 + quad * 4;
#pragma unroll
                    for (int r = 0; r < 4; ++r)
                        outb[(size_t)(p + r) * 18 + oc] = f2bf(acc[mt][nt][r]);
                }
            }
        }
    } else {
#pragma unroll
        for (int nt = 0; nt < NT; ++nt) {
            int oc = nt * 16 + m;
#pragma unroll
            for (int mt = 0; mt < 2; ++mt) {
                int wpix = p0 + mt * 16 + quad * 4;
                *(f32x4*)(outf + (((size_t)(bb * 64 + oc)) << 14) + (h << 7) + wpix) = acc[mt][nt];
            }
        }
    }
}

// ---------- deformable bilinear sample: 8x4 px tile per block, XCD-pinned by image ----------
__global__ __launch_bounds__(256, 4) void k_sample(const short* __restrict__ xt,
                                                   const short* __restrict__ offb,
                                                   short* __restrict__ smp) {
    int blk = blockIdx.x;                        // 4096 blocks
    int bb = blk & 7;                            // image = blk%8 -> XCD-pinned
    int tile = blk >> 3;                         // 0..511: 16 tiles in w, 32 in h
    int tw = tile & 15, th = tile >> 4;
    int lp = threadIdx.x >> 3;                   // local pixel 0..31 (8w x 4h)
    int ck = threadIdx.x & 7;                    // channel chunk (8 ch)
    int w = tw * 8 + (lp & 7);
    int h = th * 4 + (lp >> 3);
    int pix = (bb << 14) + (h << 7) + w;
    const short* xb = xt + ((size_t)bb << 20) + ck * 8;

    const unsigned* op = (const unsigned*)(offb + (size_t)pix * 18);
    unsigned ow[9];
#pragma unroll
    for (int j = 0; j < 9; ++j) ow[j] = op[j];

    float acc[8];
#pragma unroll
    for (int i = 0; i < 8; ++i) acc[i] = 0.f;

#pragma unroll
    for (int k = 0; k < 9; ++k) {
        float ox = bf2f((short)(ow[k] & 0xffff));
        float oy = bf2f((short)(ow[k] >> 16));
        float xs = (float)w + ox, ys = (float)h + oy;
        float x0f = floorf(xs), y0f = floorf(ys);
        float wx1 = xs - x0f, wx0 = 1.f - wx1;
        float wy1 = ys - y0f, wy0 = 1.f - wy1;
        int x0 = (int)x0f, y0 = (int)y0f;
        int x1 = x0 + 1, y1 = y0 + 1;
        int x0c = min(max(x0, 0), W_ - 1), x1c = min(max(x1, 0), W_ - 1);
        int y0c = min(max(y0, 0), H_ - 1), y1c = min(max(y1, 0), H_ - 1);
        bool vx0 = ((unsigned)x0 < W_), vx1 = ((unsigned)x1 < W_);
        bool vy0 = ((unsigned)y0 < H_), vy1 = ((unsigned)y1 < H_);
        float w00 = (vy0 && vx0) ? wy0 * wx0 : 0.f;
        float w01 = (vy0 && vx1) ? wy0 * wx1 : 0.f;
        float w10 = (vy1 && vx0) ? wy1 * wx0 : 0.f;
        float w11 = (vy1 && vx1) ? wy1 * wx1 : 0.f;
        short8 s00 = *(const short8*)(xb + ((size_t)(y0c * W_ + x0c) << 6));
        short8 s01 = *(const short8*)(xb + ((size_t)(y0c * W_ + x1c) << 6));
        short8 s10 = *(const short8*)(xb + ((size_t)(y1c * W_ + x0c) << 6));
        short8 s11 = *(const short8*)(xb + ((size_t)(y1c * W_ + x1c) << 6));
#pragma unroll
        for (int i = 0; i < 8; ++i)
            acc[i] += w00 * bf2f(s00[i]) + w01 * bf2f(s01[i])
                    + w10 * bf2f(s10[i]) + w11 * bf2f(s11[i]);
    }
    short8 o;
#pragma unroll
    for (int i = 0; i < 8; ++i) o[i] = f2bf(acc[i]);
    *(short8*)(smp + (size_t)pix * 64 + ck * 8) = o;
}

extern "C" void kernel_launch(void* const* d_in, const int* in_sizes, int n_in,
                              void* d_out, int out_size, void* d_ws, size_t ws_size,
                              hipStream_t stream) {
    const float* x   = (const float*)d_in[0];
    const float* wof = (const float*)d_in[1];
    const float* bof = (const float*)d_in[2];
    const float* wrg = (const float*)d_in[3];
    const float* brg = (const float*)d_in[4];
    float* out = (float*)d_out;

    char* ws = (char*)d_ws;
    short* xt   = (short*)ws;                                   // 16,777,216 B
    short* smp  = (short*)(ws + 16777216);                      // 16,777,216 B
    short* offb = (short*)(ws + 2 * 16777216);                  //  4,718,592 B
    short* wt1  = (short*)(ws + 2 * 16777216 + 4718592);        //     36,864 B
    short* wt2  = (short*)(ws + 2 * 16777216 + 4718592 + 36864);//     73,728 B

    k_prep <<<dim3(144), 256, 0, stream>>>(wof, wrg, wt1, wt2);
    k_tr   <<<dim3(B_ * H_), 256, 0, stream>>>(x, xt);
    k_conv<2, true>  <<<dim3(B_ * H_), 256, 0, stream>>>(xt, wt1, bof, offb, nullptr);
    k_sample<<<dim3((B_ * HW * 8) / 256), 256, 0, stream>>>(xt, offb, smp);
    k_conv<4, false> <<<dim3(B_ * H_), 256, 0, stream>>>(smp, wt2, brg, nullptr, out);
}